// Round 3
// baseline (226.785 us; speedup 1.0000x reference)
//
#include <hip/hip_runtime.h>
#include <math.h>

typedef unsigned short u16;
typedef unsigned int u32;
typedef __bf16 bf16x8 __attribute__((ext_vector_type(8)));
typedef float f32x4 __attribute__((ext_vector_type(4)));
typedef float f32x16 __attribute__((ext_vector_type(16)));

// ---------- helpers ----------
__device__ __forceinline__ u16 f2bf(float f) {
  union { float f; u32 u; } v; v.f = f;
  u32 r = v.u + 0x7fffu + ((v.u >> 16) & 1u);
  return (u16)(r >> 16);
}

__device__ __forceinline__ u32 pkbf(float a, float b) {
  u32 r;
  asm("v_cvt_pk_bf16_f32 %0, %1, %2" : "=v"(r) : "v"(a), "v"(b));
  return r;
}

// v_exp_f32 computes 2^x (log2 domain)
__device__ __forceinline__ float ex2(float x) {
  float r;
  asm("v_exp_f32 %0, %1" : "=v"(r) : "v"(x));
  return r;
}

// async global->LDS, 16B per lane. LDS dest must be wave-uniform base; HW adds lane*16.
__device__ __forceinline__ void gld16(const void* g, void* s) {
  __builtin_amdgcn_global_load_lds(
      reinterpret_cast<__attribute__((address_space(1))) u32*>((size_t)g),
      reinterpret_cast<__attribute__((address_space(3))) u32*>((u32)(size_t)s),
      16, 0, 0);
}

// ---------- prep: fp32 -> bf16 (vectorized) ----------
__global__ __launch_bounds__(256) void convk(const float* __restrict__ src,
                                             u16* __restrict__ dst, int n4) {
  int i = blockIdx.x * 256 + threadIdx.x;
  if (i >= n4) return;
  float4 v = ((const float4*)src)[i];
  uint2 o;
  o.x = (u32)f2bf(v.x) | ((u32)f2bf(v.y) << 16);
  o.y = (u32)f2bf(v.z) | ((u32)f2bf(v.w) << 16);
  ((uint2*)dst)[i] = o;
}

// ---------- prep: rel-pos LUT in LOG2 domain: lut[h][dix], dix = (s-t)+2048 ----------
__global__ __launch_bounds__(256) void lutk(const float* __restrict__ rel_emb,
                                            float* __restrict__ lut) {
  int dix = blockIdx.x * 256 + threadIdx.x;
  if (dix >= 4096) return;
  int rp = dix - 2048;                 // rp = s - t
  int bucket = (rp > 0) ? 16 : 0;
  int rpa = rp < 0 ? -rp : rp;
  if (rpa < 8) {
    bucket += rpa;
  } else {
    int large = 8 + (int)(logf((float)rpa * 0.125f) * (8.0f / 2.772588722239781f));
    bucket += (large < 15) ? large : 15;
  }
  const float LOG2E = 1.4426950408889634f;
#pragma unroll
  for (int h = 0; h < 16; ++h) lut[h * 4096 + dix] = rel_emb[bucket * 16 + h] * LOG2E;
}

// ---------- prep: gate_a_1[b,h,t] (exact fp32) ----------
__global__ __launch_bounds__(256) void gatek(const float* __restrict__ query,
                                             const float* __restrict__ grep_w,
                                             const float* __restrict__ grep_b,
                                             const float* __restrict__ grep_a,
                                             float* __restrict__ gate) {
  __shared__ __align__(16) float gw[8][64];
  __shared__ float gb[8];
  __shared__ float ga[16];
  int tid = threadIdx.x;
  if (tid < 128) ((float4*)&gw[0][0])[tid] = ((const float4*)grep_w)[tid];
  if (tid < 8) gb[tid] = grep_b[tid];
  if (tid < 16) ga[tid] = grep_a[tid];
  __syncthreads();
  int i = blockIdx.x * 256 + tid;          // i = ((b*16+h)*2048 + t)
  int t = i & 2047, h = (i >> 11) & 15, b = i >> 15;
  const float* x = query + ((size_t)t * 2 + b) * 1024 + h * 64;
  float acc[8] = {0, 0, 0, 0, 0, 0, 0, 0};
  for (int e4 = 0; e4 < 16; ++e4) {
    float4 xv = ((const float4*)x)[e4];
#pragma unroll
    for (int j = 0; j < 8; ++j)
      acc[j] += xv.x * gw[j][e4 * 4] + xv.y * gw[j][e4 * 4 + 1] +
                xv.z * gw[j][e4 * 4 + 2] + xv.w * gw[j][e4 * 4 + 3];
  }
  float sA = acc[0] + acc[1] + acc[2] + acc[3] + gb[0] + gb[1] + gb[2] + gb[3];
  float sB = acc[4] + acc[5] + acc[6] + acc[7] + gb[4] + gb[5] + gb[6] + gb[7];
  float gA = 1.0f / (1.0f + expf(-sA));
  float gB = 1.0f / (1.0f + expf(-sB));
  gate[i] = gA * (gB * ga[h] - 1.0f) + 2.0f;
}

// ---------- GEMM: C[m][n] = A[m][:] . W[n][:] (+bias), bf16 MFMA, 128x128 tile, BK=64 ----------
__global__ __launch_bounds__(256) void gemmk(
    const u16* __restrict__ A,
    const u16* __restrict__ W0, const u16* __restrict__ W1, const u16* __restrict__ W2,
    const float* __restrict__ b0, const float* __restrict__ b1, const float* __restrict__ b2,
    u16* __restrict__ qa, u16* __restrict__ ka, u16* __restrict__ vt,
    float* __restrict__ fout, int moBase) {
  const int mode = moBase + (int)blockIdx.z;
  const u16* W = (mode == 1) ? W1 : (mode == 2) ? W2 : W0;
  const float* bias = (mode == 1) ? b1 : (mode == 2) ? b2 : b0;

  __shared__ __align__(16) u16 As[128 * 64];   // [row][64] bf16, 8 16B-slots/row, slot^=(row&7)
  __shared__ __align__(16) u16 Bs[128 * 64];

  const int tid = threadIdx.x;
  const int l = tid & 63;
  const int w = tid >> 6;
  const int wr = w >> 1, wc = w & 1;
  const int m0 = blockIdx.y * 128, n0 = blockIdx.x * 128;
  const int li = l >> 3, ls = l & 7;

  f32x4 acc[4][4] = {};

  for (int k0 = 0; k0 < 1024; k0 += 64) {
#pragma unroll
    for (int j = 0; j < 4; ++j) {
      const int rr = (w * 4 + j) * 8 + li;
      const int cs = ls ^ (rr & 7);
      gld16(A + ((size_t)(m0 + rr) << 10) + k0 + cs * 8, &As[(w * 4 + j) * 512]);
      gld16(W + ((size_t)(n0 + rr) << 10) + k0 + cs * 8, &Bs[(w * 4 + j) * 512]);
    }
    __syncthreads();
#pragma unroll
    for (int ks = 0; ks < 2; ++ks) {
      bf16x8 af[4], bfr[4];
#pragma unroll
      for (int mf = 0; mf < 4; ++mf) {
        const int row = wr * 64 + mf * 16 + (l & 15);
        const int slot = (ks * 4 + (l >> 4)) ^ (row & 7);
        af[mf] = *(const bf16x8*)&As[row * 64 + slot * 8];
      }
#pragma unroll
      for (int nf = 0; nf < 4; ++nf) {
        const int row = wc * 64 + nf * 16 + (l & 15);
        const int slot = (ks * 4 + (l >> 4)) ^ (row & 7);
        bfr[nf] = *(const bf16x8*)&Bs[row * 64 + slot * 8];
      }
#pragma unroll
      for (int mf = 0; mf < 4; ++mf)
#pragma unroll
        for (int nf = 0; nf < 4; ++nf)
          acc[mf][nf] = __builtin_amdgcn_mfma_f32_16x16x32_bf16(af[mf], bfr[nf], acc[mf][nf], 0, 0, 0);
    }
    __syncthreads();
  }

  const float QSC = 0.125f * 1.4426950408889634f;  // HD^-0.5 * log2(e): Q in log2 domain
#pragma unroll
  for (int mf = 0; mf < 4; ++mf)
#pragma unroll
    for (int nf = 0; nf < 4; ++nf)
#pragma unroll
      for (int r = 0; r < 4; ++r) {
        const int row = m0 + wr * 64 + mf * 16 + (l >> 4) * 4 + r;  // m = t*2+b
        const int col = n0 + wc * 64 + nf * 16 + (l & 15);          // n = h*64+d
        float v = acc[mf][nf][r] + bias[col];
        const int t = row >> 1, bb = row & 1, hh = col >> 6, d = col & 63;
        if (mode == 0) {
          v *= QSC;
          qa[((((size_t)bb * 16 + hh) * 2048 + t) << 6) + d] = f2bf(v);
        } else if (mode == 1) {
          ka[((((size_t)bb * 16 + hh) * 2048 + t) << 6) + d] = f2bf(v);
        } else if (mode == 2) {
          vt[((((size_t)bb * 16 + hh) * 64 + d) << 11) + t] = f2bf(v);
        } else {
          fout[((size_t)row << 10) + col] = v;
        }
      }
}

// ---------- flash attention, swapped-QK^T 32x32, in-block KV-split x4 ----------
// grid: 2048 blocks (64 q-tiles x 32 bh), 4 waves each own a 512-KV quarter of the
// SAME 32 q-rows; LDS combine at the end. Softmax in log2 domain (Q,lut pre-scaled).
// Far-band: bias constant for |s-t|>=91 -> no lut reads outside +-90 diagonal band.
__global__ __launch_bounds__(256, 4) void flashk(const u16* __restrict__ qa,
                                                 const u16* __restrict__ ka,
                                                 const u16* __restrict__ vt,
                                                 const float* __restrict__ lutg,
                                                 const float* __restrict__ gatew,
                                                 u16* __restrict__ aout) {
  const int B = blockIdx.x;
  const int xcd = B & 7, j = B >> 3;
  const int bh = xcd * 4 + (j >> 6);       // 4 heads per XCD
  const int qt = j & 63;
  const int hh = bh & 15, b = bh >> 4;
  const int tid = threadIdx.x, l = tid & 63, w = tid >> 6;
  const int hi = l >> 5, q = l & 31;
  const int q0 = qt * 32;
  const int qg = q0 + q;                   // global q row

  __shared__ __align__(16) float slice[320];          // lut band, dix0 = 1920
  __shared__ float cmS[4][32], clS[4][32];
  __shared__ __align__(16) float4 cOS[4][32][16];     // [w][q][slot] 16B, slot^=(q&15)

  for (int i = tid; i < 288; i += 256) slice[i] = lutg[hh * 4096 + 1920 + i];
  __syncthreads();

  const u16* Q = qa + ((size_t)bh << 17);
  const u16* K = ka + ((size_t)bh << 17);
  const u16* V = vt + ((size_t)bh << 17);

  // Q B-frags: lane n=q, k-dim = mk*16 + hi*8 + j
  bf16x8 qf[4];
#pragma unroll
  for (int mk = 0; mk < 4; ++mk)
    qf[mk] = *(const bf16x8*)&Q[((size_t)qg << 6) + mk * 16 + hi * 8];

  const float g = gatew[((size_t)bh << 11) + qg];
  const float gcm = g * lutg[hh * 4096];          // far-minus bias (log2 dom)
  const float gcp = g * lutg[hh * 4096 + 4095];   // far-plus bias

  float m_run = -3e38f, l_run = 0.0f;
  f32x16 oacc[2] = {};

  const int sBeg = w * 512, sEnd = sBeg + 512;
  for (int s0 = sBeg; s0 < sEnd; s0 += 32) {
    // S^T tile: C[k_local][q], k_local = (reg&3)+8*(reg>>2)+4*hi
    f32x16 s = {};
#pragma unroll
    for (int mk = 0; mk < 4; ++mk) {
      bf16x8 kf = *(const bf16x8*)&K[((size_t)(s0 + q) << 6) + mk * 16 + hi * 8];
      s = __builtin_amdgcn_mfma_f32_32x32x16_bf16(kf, qf[mk], s, 0, 0, 0);
    }
    const int kt = (s0 - q0) >> 5;         // tile offset (arith shift = floor)
    const bool far = (kt <= -4) | (kt >= 4);
    float gc = 0.0f;
    float mx = -3e38f;
    if (far) {
      gc = (kt < 0) ? gcm : gcp;
#pragma unroll
      for (int reg = 0; reg < 16; ++reg) mx = fmaxf(mx, s[reg]);
      mx = fmaxf(mx, __shfl_xor(mx, 32, 64)) + gc;
    } else {
      const int sb = s0 - q0 + 128 + 4 * hi - q;   // slice index base (in [1,255])
#pragma unroll
      for (int reg = 0; reg < 16; ++reg) {
        const int kloc = (reg & 3) + 8 * (reg >> 2);
        const float v = fmaf(g, slice[sb + kloc], s[reg]);
        s[reg] = v;
        mx = fmaxf(mx, v);
      }
      mx = fmaxf(mx, __shfl_xor(mx, 32, 64));
    }
    // defer-max (T13), log2 domain threshold 8*log2e ~ 11.5
    if (!__all(mx - m_run <= 11.5f)) {
      const float mnew = fmaxf(m_run, mx);
      const float sc = ex2(m_run - mnew);
      l_run *= sc;
#pragma unroll
      for (int r = 0; r < 16; ++r) { oacc[0][r] *= sc; oacc[1][r] *= sc; }
      m_run = mnew;
    }
    // P = 2^(S - mref), row sum (far: constant bias folded into mref)
    const float mref = m_run - gc;
    float rsum = 0.0f;
#pragma unroll
    for (int reg = 0; reg < 16; ++reg) {
      const float p = ex2(s[reg] - mref);
      s[reg] = p;
      rsum += p;
    }
    rsum += __shfl_xor(rsum, 32, 64);
    l_run += rsum;
    // pack P -> PV B-frags (T12)
    bf16x8 pa[2];
#pragma unroll
    for (int kh = 0; kh < 2; ++kh) {
      const int rb = kh * 8;
      const u32 X0 = pkbf(s[rb + 0], s[rb + 1]);
      const u32 X1 = pkbf(s[rb + 2], s[rb + 3]);
      const u32 Y0 = pkbf(s[rb + 4], s[rb + 5]);
      const u32 Y1 = pkbf(s[rb + 6], s[rb + 7]);
      const u32 E0 = hi ? X0 : Y0;
      const u32 E1 = hi ? X1 : Y1;
      const u32 Ep0 = (u32)__shfl_xor((int)E0, 32, 64);
      const u32 Ep1 = (u32)__shfl_xor((int)E1, 32, 64);
      union { u32 wds[4]; bf16x8 v; } pu;
      pu.wds[0] = hi ? Ep0 : X0;
      pu.wds[1] = hi ? Ep1 : X1;
      pu.wds[2] = hi ? Y0 : Ep0;
      pu.wds[3] = hi ? Y1 : Ep1;
      pa[kh] = pu.v;
    }
    // O^T += V^T . P
#pragma unroll
    for (int dt = 0; dt < 2; ++dt)
#pragma unroll
      for (int kh = 0; kh < 2; ++kh) {
        bf16x8 vf = *(const bf16x8*)&V[((size_t)(dt * 32 + q) << 11) + s0 + kh * 16 + hi * 8];
        oacc[dt] = __builtin_amdgcn_mfma_f32_32x32x16_bf16(vf, pa[kh], oacc[dt], 0, 0, 0);
      }
  }

  // ---- write per-wave partials to LDS ----
  if (hi == 0) { cmS[w][q] = m_run; clS[w][q] = l_run; }
#pragma unroll
  for (int dt = 0; dt < 2; ++dt)
#pragma unroll
    for (int g4 = 0; g4 < 4; ++g4) {
      float4 v4;
      v4.x = oacc[dt][g4 * 4 + 0];
      v4.y = oacc[dt][g4 * 4 + 1];
      v4.z = oacc[dt][g4 * 4 + 2];
      v4.w = oacc[dt][g4 * 4 + 3];
      const int slot = dt * 8 + g4 * 2 + hi;        // = d>>2, d = dt*32+8*g4+4*hi+(reg&3)
      cOS[w][q][slot ^ (q & 15)] = v4;
    }
  __syncthreads();

  // ---- combine: thread t -> (q = t>>3, d0 = (t&7)*8) ----
  const int cq = tid >> 3, d0 = (tid & 7) * 8;
  float M = fmaxf(fmaxf(cmS[0][cq], cmS[1][cq]), fmaxf(cmS[2][cq], cmS[3][cq]));
  float lsum = 0.0f;
  float o[8] = {0, 0, 0, 0, 0, 0, 0, 0};
#pragma unroll
  for (int w4 = 0; w4 < 4; ++w4) {
    const float e = ex2(cmS[w4][cq] - M);
    lsum += clS[w4][cq] * e;
    const int sl0 = d0 >> 2;
    const float4 a = cOS[w4][cq][(sl0 + 0) ^ (cq & 15)];
    const float4 c = cOS[w4][cq][(sl0 + 1) ^ (cq & 15)];
    o[0] += a.x * e; o[1] += a.y * e; o[2] += a.z * e; o[3] += a.w * e;
    o[4] += c.x * e; o[5] += c.y * e; o[6] += c.z * e; o[7] += c.w * e;
  }
  const float inv = 1.0f / lsum;
  union { u16 hb[8]; uint4 u4; } st;
#pragma unroll
  for (int jj = 0; jj < 8; ++jj) st.hb[jj] = f2bf(o[jj] * inv);
  *(uint4*)&aout[(((size_t)(q0 + cq) * 2 + b) << 10) + hh * 64 + d0] = st.u4;
}

// ---------- launch ----------
extern "C" void kernel_launch(void* const* d_in, const int* in_sizes, int n_in,
                              void* d_out, int out_size, void* d_ws, size_t ws_size,
                              hipStream_t stream) {
  (void)in_sizes; (void)n_in; (void)out_size; (void)ws_size;
  const float* query  = (const float*)d_in[0];
  const float* q_w    = (const float*)d_in[1];
  const float* q_b    = (const float*)d_in[2];
  const float* k_w    = (const float*)d_in[3];
  const float* k_b    = (const float*)d_in[4];
  const float* v_w    = (const float*)d_in[5];
  const float* v_b    = (const float*)d_in[6];
  const float* out_w  = (const float*)d_in[7];
  const float* out_b  = (const float*)d_in[8];
  const float* rel_emb= (const float*)d_in[9];
  const float* grep_w = (const float*)d_in[10];
  const float* grep_b = (const float*)d_in[11];
  const float* grep_a = (const float*)d_in[12];

  char* ws = (char*)d_ws;
  const size_t MB = 1ull << 20;
  u16* qbf  = (u16*)(ws + 0 * MB);      // 8MB  query bf16 (t,b,e)
  u16* wqb  = (u16*)(ws + 8 * MB);      // 2MB
  u16* wkb  = (u16*)(ws + 10 * MB);
  u16* wvb  = (u16*)(ws + 12 * MB);
  u16* wob  = (u16*)(ws + 14 * MB);
  u16* qav  = (u16*)(ws + 16 * MB);     // 8MB  [b,h,t,d] (log2-scaled Q)
  u16* kav  = (u16*)(ws + 24 * MB);     // 8MB  [b,h,t,d]
  u16* vtv  = (u16*)(ws + 32 * MB);     // 8MB  [b,h,d,t]
  u16* aout = (u16*)(ws + 40 * MB);     // 8MB  attn out (t,b,e) bf16
  float* lut  = (float*)(ws + 48 * MB);              // 256KB [h][4096], log2 dom
  float* gate = (float*)(ws + 48 * MB + 256 * 1024); // 256KB [b,h,t]

  convk<<<dim3(4096), 256, 0, stream>>>(query, qbf, 1048576);
  convk<<<dim3(1024), 256, 0, stream>>>(q_w, wqb, 262144);
  convk<<<dim3(1024), 256, 0, stream>>>(k_w, wkb, 262144);
  convk<<<dim3(1024), 256, 0, stream>>>(v_w, wvb, 262144);
  convk<<<dim3(1024), 256, 0, stream>>>(out_w, wob, 262144);
  lutk<<<dim3(16), 256, 0, stream>>>(rel_emb, lut);
  gatek<<<dim3(256), 256, 0, stream>>>(query, grep_w, grep_b, grep_a, gate);

  gemmk<<<dim3(8, 32, 3), 256, 0, stream>>>(qbf, wqb, wkb, wvb, q_b, k_b, v_b,
                                            qav, kav, vtv, nullptr, 0);
  flashk<<<dim3(2048), 256, 0, stream>>>(qav, kav, vtv, lut, gate, aout);
  gemmk<<<dim3(8, 32, 1), 256, 0, stream>>>(aout, wob, nullptr, nullptr, out_b, nullptr, nullptr,
                                            nullptr, nullptr, nullptr, (float*)d_out, 3);
}

// Round 4
// 183.637 us; speedup vs baseline: 1.2350x; 1.2350x over previous
//
#include <hip/hip_runtime.h>
#include <math.h>

typedef unsigned short u16;
typedef unsigned int u32;
typedef __bf16 bf16x8 __attribute__((ext_vector_type(8)));
typedef float f32x4 __attribute__((ext_vector_type(4)));
typedef float f32x16 __attribute__((ext_vector_type(16)));

// ---------- helpers ----------
__device__ __forceinline__ u16 f2bf(float f) {
  union { float f; u32 u; } v; v.f = f;
  u32 r = v.u + 0x7fffu + ((v.u >> 16) & 1u);
  return (u16)(r >> 16);
}

__device__ __forceinline__ u32 pkbf(float a, float b) {
  u32 r;
  asm("v_cvt_pk_bf16_f32 %0, %1, %2" : "=v"(r) : "v"(a), "v"(b));
  return r;
}

// v_exp_f32 computes 2^x (log2 domain)
__device__ __forceinline__ float ex2(float x) {
  float r;
  asm("v_exp_f32 %0, %1" : "=v"(r) : "v"(x));
  return r;
}

// async global->LDS, 16B per lane. LDS dest wave-uniform base; HW adds lane*16.
// Global source IS per-lane -> pre-swizzled source + swizzled ds_read (rule #21).
__device__ __forceinline__ void gld16(const void* g, void* s) {
  __builtin_amdgcn_global_load_lds(
      reinterpret_cast<__attribute__((address_space(1))) u32*>((size_t)g),
      reinterpret_cast<__attribute__((address_space(3))) u32*>((u32)(size_t)s),
      16, 0, 0);
}

// ---------- prep: fp32 -> bf16 (vectorized) ----------
__global__ __launch_bounds__(256) void convk(const float* __restrict__ src,
                                             u16* __restrict__ dst, int n4) {
  int i = blockIdx.x * 256 + threadIdx.x;
  if (i >= n4) return;
  float4 v = ((const float4*)src)[i];
  uint2 o;
  o.x = (u32)f2bf(v.x) | ((u32)f2bf(v.y) << 16);
  o.y = (u32)f2bf(v.z) | ((u32)f2bf(v.w) << 16);
  ((uint2*)dst)[i] = o;
}

// ---------- prep: rel-pos LUT in LOG2 domain: lut[h][dix], dix = (s-t)+2048 ----------
__global__ __launch_bounds__(256) void lutk(const float* __restrict__ rel_emb,
                                            float* __restrict__ lut) {
  int dix = blockIdx.x * 256 + threadIdx.x;
  if (dix >= 4096) return;
  int rp = dix - 2048;                 // rp = s - t
  int bucket = (rp > 0) ? 16 : 0;
  int rpa = rp < 0 ? -rp : rp;
  if (rpa < 8) {
    bucket += rpa;
  } else {
    int large = 8 + (int)(logf((float)rpa * 0.125f) * (8.0f / 2.772588722239781f));
    bucket += (large < 15) ? large : 15;
  }
  const float LOG2E = 1.4426950408889634f;
#pragma unroll
  for (int h = 0; h < 16; ++h) lut[h * 4096 + dix] = rel_emb[bucket * 16 + h] * LOG2E;
}

// ---------- prep: gate_a_1[b,h,t] (exact fp32) ----------
__global__ __launch_bounds__(256) void gatek(const float* __restrict__ query,
                                             const float* __restrict__ grep_w,
                                             const float* __restrict__ grep_b,
                                             const float* __restrict__ grep_a,
                                             float* __restrict__ gate) {
  __shared__ __align__(16) float gw[8][64];
  __shared__ float gb[8];
  __shared__ float ga[16];
  int tid = threadIdx.x;
  if (tid < 128) ((float4*)&gw[0][0])[tid] = ((const float4*)grep_w)[tid];
  if (tid < 8) gb[tid] = grep_b[tid];
  if (tid < 16) ga[tid] = grep_a[tid];
  __syncthreads();
  int i = blockIdx.x * 256 + tid;          // i = ((b*16+h)*2048 + t)
  int t = i & 2047, h = (i >> 11) & 15, b = i >> 15;
  const float* x = query + ((size_t)t * 2 + b) * 1024 + h * 64;
  float acc[8] = {0, 0, 0, 0, 0, 0, 0, 0};
  for (int e4 = 0; e4 < 16; ++e4) {
    float4 xv = ((const float4*)x)[e4];
#pragma unroll
    for (int j = 0; j < 8; ++j)
      acc[j] += xv.x * gw[j][e4 * 4] + xv.y * gw[j][e4 * 4 + 1] +
                xv.z * gw[j][e4 * 4 + 2] + xv.w * gw[j][e4 * 4 + 3];
  }
  float sA = acc[0] + acc[1] + acc[2] + acc[3] + gb[0] + gb[1] + gb[2] + gb[3];
  float sB = acc[4] + acc[5] + acc[6] + acc[7] + gb[4] + gb[5] + gb[6] + gb[7];
  float gA = 1.0f / (1.0f + expf(-sA));
  float gB = 1.0f / (1.0f + expf(-sB));
  gate[i] = gA * (gB * ga[h] - 1.0f) + 2.0f;
}

// ---------- GEMM: C[m][n] = A[m][:] . W[n][:] (+bias), bf16 MFMA, 128x128 tile, BK=64 ----------
__global__ __launch_bounds__(256) void gemmk(
    const u16* __restrict__ A,
    const u16* __restrict__ W0, const u16* __restrict__ W1, const u16* __restrict__ W2,
    const float* __restrict__ b0, const float* __restrict__ b1, const float* __restrict__ b2,
    u16* __restrict__ qa, u16* __restrict__ ka, u16* __restrict__ vt,
    float* __restrict__ fout, int moBase) {
  const int mode = moBase + (int)blockIdx.z;
  const u16* W = (mode == 1) ? W1 : (mode == 2) ? W2 : W0;
  const float* bias = (mode == 1) ? b1 : (mode == 2) ? b2 : b0;

  __shared__ __align__(16) u16 As[128 * 64];   // [row][64] bf16, 8 16B-slots/row, slot^=(row&7)
  __shared__ __align__(16) u16 Bs[128 * 64];

  const int tid = threadIdx.x;
  const int l = tid & 63;
  const int w = tid >> 6;
  const int wr = w >> 1, wc = w & 1;
  const int m0 = blockIdx.y * 128, n0 = blockIdx.x * 128;
  const int li = l >> 3, ls = l & 7;

  f32x4 acc[4][4] = {};

  for (int k0 = 0; k0 < 1024; k0 += 64) {
#pragma unroll
    for (int j = 0; j < 4; ++j) {
      const int rr = (w * 4 + j) * 8 + li;
      const int cs = ls ^ (rr & 7);
      gld16(A + ((size_t)(m0 + rr) << 10) + k0 + cs * 8, &As[(w * 4 + j) * 512]);
      gld16(W + ((size_t)(n0 + rr) << 10) + k0 + cs * 8, &Bs[(w * 4 + j) * 512]);
    }
    __syncthreads();
#pragma unroll
    for (int ks = 0; ks < 2; ++ks) {
      bf16x8 af[4], bfr[4];
#pragma unroll
      for (int mf = 0; mf < 4; ++mf) {
        const int row = wr * 64 + mf * 16 + (l & 15);
        const int slot = (ks * 4 + (l >> 4)) ^ (row & 7);
        af[mf] = *(const bf16x8*)&As[row * 64 + slot * 8];
      }
#pragma unroll
      for (int nf = 0; nf < 4; ++nf) {
        const int row = wc * 64 + nf * 16 + (l & 15);
        const int slot = (ks * 4 + (l >> 4)) ^ (row & 7);
        bfr[nf] = *(const bf16x8*)&Bs[row * 64 + slot * 8];
      }
#pragma unroll
      for (int mf = 0; mf < 4; ++mf)
#pragma unroll
        for (int nf = 0; nf < 4; ++nf)
          acc[mf][nf] = __builtin_amdgcn_mfma_f32_16x16x32_bf16(af[mf], bfr[nf], acc[mf][nf], 0, 0, 0);
    }
    __syncthreads();
  }

  const float QSC = 0.125f * 1.4426950408889634f;  // HD^-0.5 * log2(e): Q in log2 domain
#pragma unroll
  for (int mf = 0; mf < 4; ++mf)
#pragma unroll
    for (int nf = 0; nf < 4; ++nf)
#pragma unroll
      for (int r = 0; r < 4; ++r) {
        const int row = m0 + wr * 64 + mf * 16 + (l >> 4) * 4 + r;  // m = t*2+b
        const int col = n0 + wc * 64 + nf * 16 + (l & 15);          // n = h*64+d
        float v = acc[mf][nf][r] + bias[col];
        const int t = row >> 1, bb = row & 1, hh = col >> 6, d = col & 63;
        if (mode == 0) {
          v *= QSC;
          qa[((((size_t)bb * 16 + hh) * 2048 + t) << 6) + d] = f2bf(v);
        } else if (mode == 1) {
          ka[((((size_t)bb * 16 + hh) * 2048 + t) << 6) + d] = f2bf(v);
        } else if (mode == 2) {
          vt[((((size_t)bb * 16 + hh) * 64 + d) << 11) + t] = f2bf(v);
        } else {
          fout[((size_t)row << 10) + col] = v;
        }
      }
}

// ---------- flash attention v3: swapped-QK^T 32x32, LDS-staged K/V shared by 4 waves ----------
// Block = 128 q-rows (4 waves x 32); all waves iterate the same 64 KV-tiles.
// Per step: stage next K(4KB)+V(4KB) tile coalesced via global_load_lds (2 issues/wave),
// read fragments via swizzled ds_read_b128. Softmax in log2 domain; far-band constant
// bias (|s-t|>=97 clamped); defer-max. One __syncthreads per step (drain = depth-1 pipe).
__global__ __launch_bounds__(256) void flashk(const u16* __restrict__ qa,
                                              const u16* __restrict__ ka,
                                              const u16* __restrict__ vt,
                                              const float* __restrict__ lutg,
                                              const float* __restrict__ gatew,
                                              u16* __restrict__ aout) {
  const int B = blockIdx.x;
  const int xcd = B & 7, j = B >> 3;
  const int bh = xcd * 4 + (j >> 4);       // 4 heads per XCD (L2-resident K/V)
  const int qt = j & 15;
  const int hh = bh & 15, b = bh >> 4;
  const int tid = threadIdx.x, l = tid & 63, w = tid >> 6;
  const int hi = l >> 5, q = l & 31;
  const int q0w = qt * 128 + w * 32;       // this wave's q-tile base
  const int qg = q0w + q;                  // global q row

  // K tile: [32 s-rows][64 d] bf16, 8 slots/row, slot^=(row&7)
  // V tile: [64 d-rows][32 s] bf16, 4 slots/row, slot^=(row&3)
  __shared__ __align__(16) u16 Kbuf[2][32 * 64];
  __shared__ __align__(16) u16 Vbuf[2][64 * 32];
  __shared__ __align__(16) float slice[288];   // lut band, dix0 = 1920 -> (s-t) in [-128,160)

  for (int i = tid; i < 288; i += 256) slice[i] = lutg[hh * 4096 + 1920 + i];

  const u16* Q = qa + ((size_t)bh << 17);
  const u16* K = ka + ((size_t)bh << 17);
  const u16* V = vt + ((size_t)bh << 17);

  // staging lane decompositions
  const int kli = l >> 3, kls = l & 7;     // K: lane -> (row 8w+kli, slot kls)
  const int vli = l >> 2, vls = l & 3;     // V: lane -> (row 16w+vli, slot vls)
  const u16* Ksrc = K + ((size_t)(w * 8 + kli) << 6) + ((kls ^ kli) << 3);
  const u16* Vsrc = V + ((size_t)(w * 16 + vli) << 11) + ((vls ^ (vli & 3)) << 3);
  u16* KdstA = &Kbuf[0][w * 512]; u16* KdstB = &Kbuf[1][w * 512];
  u16* VdstA = &Vbuf[0][w * 512]; u16* VdstB = &Vbuf[1][w * 512];

  // Q B-frags: lane n=q, k-dim = mk*16 + hi*8 + j
  bf16x8 qf[4];
#pragma unroll
  for (int mk = 0; mk < 4; ++mk)
    qf[mk] = *(const bf16x8*)&Q[((size_t)qg << 6) + mk * 16 + hi * 8];

  const float g = gatew[((size_t)bh << 11) + qg];
  const float gcm = g * lutg[hh * 4096];          // far-minus bias (log2 dom)
  const float gcp = g * lutg[hh * 4096 + 4095];   // far-plus bias

  float m_run = -3e38f, l_run = 0.0f;
  f32x16 oacc[2] = {};

  // prologue: stage tile 0 into buf 0
  gld16(Ksrc, KdstA);
  gld16(Vsrc, VdstA);
  __syncthreads();   // drains vmcnt + barrier: tile 0 + slice ready

  for (int ts = 0; ts < 64; ++ts) {
    const int s0 = ts * 32;
    const int bf = ts & 1;
    // prefetch next tile into other buffer (coalesced, shared by all 4 waves)
    if (ts < 63) {
      const size_t soff = (size_t)(s0 + 32);
      gld16(Ksrc + (soff << 6), bf ? KdstA : KdstB);
      gld16(Vsrc + soff, bf ? VdstA : VdstB);
    }
    const u16* Kb = &Kbuf[bf][0];
    const u16* Vb = &Vbuf[bf][0];

    // S^T tile: C[k_local][q], k_local = (reg&3)+8*(reg>>2)+4*hi
    f32x16 s = {};
#pragma unroll
    for (int mk = 0; mk < 4; ++mk) {
      bf16x8 kf = *(const bf16x8*)&Kb[q * 64 + (((mk * 2 + hi) ^ (q & 7)) << 3)];
      s = __builtin_amdgcn_mfma_f32_32x32x16_bf16(kf, qf[mk], s, 0, 0, 0);
    }

    const int kt = (s0 - q0w) >> 5;
    const bool far = (kt <= -4) | (kt >= 4);
    float gc = 0.0f;
    float mx;
    if (far) {
      gc = (kt < 0) ? gcm : gcp;
      float m0_ = fmaxf(fmaxf(s[0], s[1]), fmaxf(s[2], s[3]));
      float m1_ = fmaxf(fmaxf(s[4], s[5]), fmaxf(s[6], s[7]));
      float m2_ = fmaxf(fmaxf(s[8], s[9]), fmaxf(s[10], s[11]));
      float m3_ = fmaxf(fmaxf(s[12], s[13]), fmaxf(s[14], s[15]));
      mx = fmaxf(fmaxf(m0_, m1_), fmaxf(m2_, m3_));
      mx = fmaxf(mx, __shfl_xor(mx, 32, 64)) + gc;
    } else {
      const int sb = s0 - q0w + 128 + 4 * hi - q;
#pragma unroll
      for (int reg = 0; reg < 16; ++reg) {
        const int kloc = (reg & 3) + 8 * (reg >> 2);
        s[reg] = fmaf(g, slice[sb + kloc], s[reg]);
      }
      float m0_ = fmaxf(fmaxf(s[0], s[1]), fmaxf(s[2], s[3]));
      float m1_ = fmaxf(fmaxf(s[4], s[5]), fmaxf(s[6], s[7]));
      float m2_ = fmaxf(fmaxf(s[8], s[9]), fmaxf(s[10], s[11]));
      float m3_ = fmaxf(fmaxf(s[12], s[13]), fmaxf(s[14], s[15]));
      mx = fmaxf(fmaxf(m0_, m1_), fmaxf(m2_, m3_));
      mx = fmaxf(mx, __shfl_xor(mx, 32, 64));
    }
    // defer-max (T13), log2 domain threshold ~ 8*log2e
    if (!__all(mx - m_run <= 11.5f)) {
      const float mnew = fmaxf(m_run, mx);
      const float sc = ex2(m_run - mnew);
      l_run *= sc;
#pragma unroll
      for (int r = 0; r < 16; ++r) { oacc[0][r] *= sc; oacc[1][r] *= sc; }
      m_run = mnew;
    }
    // P = 2^(S - mref), tree row-sum
    const float mref = m_run - gc;
#pragma unroll
    for (int reg = 0; reg < 16; ++reg) s[reg] = ex2(s[reg] - mref);
    {
      float r0 = (s[0] + s[1]) + (s[2] + s[3]);
      float r1 = (s[4] + s[5]) + (s[6] + s[7]);
      float r2 = (s[8] + s[9]) + (s[10] + s[11]);
      float r3 = (s[12] + s[13]) + (s[14] + s[15]);
      float rsum = (r0 + r1) + (r2 + r3);
      rsum += __shfl_xor(rsum, 32, 64);
      l_run += rsum;
    }
    // pack P -> PV B-frags (T12)
    bf16x8 pa[2];
#pragma unroll
    for (int kh = 0; kh < 2; ++kh) {
      const int rb = kh * 8;
      const u32 X0 = pkbf(s[rb + 0], s[rb + 1]);
      const u32 X1 = pkbf(s[rb + 2], s[rb + 3]);
      const u32 Y0 = pkbf(s[rb + 4], s[rb + 5]);
      const u32 Y1 = pkbf(s[rb + 6], s[rb + 7]);
      const u32 E0 = hi ? X0 : Y0;
      const u32 E1 = hi ? X1 : Y1;
      const u32 Ep0 = (u32)__shfl_xor((int)E0, 32, 64);
      const u32 Ep1 = (u32)__shfl_xor((int)E1, 32, 64);
      union { u32 wds[4]; bf16x8 v; } pu;
      pu.wds[0] = hi ? Ep0 : X0;
      pu.wds[1] = hi ? Ep1 : X1;
      pu.wds[2] = hi ? Y0 : Ep0;
      pu.wds[3] = hi ? Y1 : Ep1;
      pa[kh] = pu.v;
    }
    // O^T += V^T . P  (V frags from LDS, swizzled)
#pragma unroll
    for (int dt = 0; dt < 2; ++dt)
#pragma unroll
      for (int kh = 0; kh < 2; ++kh) {
        bf16x8 vf = *(const bf16x8*)&Vb[(dt * 32 + q) * 32 + (((kh * 2 + hi) ^ (q & 3)) << 3)];
        oacc[dt] = __builtin_amdgcn_mfma_f32_32x32x16_bf16(vf, pa[kh], oacc[dt], 0, 0, 0);
      }
    __syncthreads();  // next tile staged (vmcnt drained) + all waves done reading buf
  }

  // epilogue: O[q][d] = oacc/l_run ; d = dt*32 + gph*8 + hi*4 + r
  const float inv = 1.0f / l_run;
#pragma unroll
  for (int dt = 0; dt < 2; ++dt)
#pragma unroll
    for (int gph = 0; gph < 4; ++gph) {
      const int d0 = dt * 32 + gph * 8 + hi * 4;
      uint2 st;
      st.x = pkbf(oacc[dt][gph * 4 + 0] * inv, oacc[dt][gph * 4 + 1] * inv);
      st.y = pkbf(oacc[dt][gph * 4 + 2] * inv, oacc[dt][gph * 4 + 3] * inv);
      *(uint2*)&aout[(((size_t)qg * 2 + b) << 10) + hh * 64 + d0] = st;
    }
}

// ---------- launch ----------
extern "C" void kernel_launch(void* const* d_in, const int* in_sizes, int n_in,
                              void* d_out, int out_size, void* d_ws, size_t ws_size,
                              hipStream_t stream) {
  (void)in_sizes; (void)n_in; (void)out_size; (void)ws_size;
  const float* query  = (const float*)d_in[0];
  const float* q_w    = (const float*)d_in[1];
  const float* q_b    = (const float*)d_in[2];
  const float* k_w    = (const float*)d_in[3];
  const float* k_b    = (const float*)d_in[4];
  const float* v_w    = (const float*)d_in[5];
  const float* v_b    = (const float*)d_in[6];
  const float* out_w  = (const float*)d_in[7];
  const float* out_b  = (const float*)d_in[8];
  const float* rel_emb= (const float*)d_in[9];
  const float* grep_w = (const float*)d_in[10];
  const float* grep_b = (const float*)d_in[11];
  const float* grep_a = (const float*)d_in[12];

  char* ws = (char*)d_ws;
  const size_t MB = 1ull << 20;
  u16* qbf  = (u16*)(ws + 0 * MB);      // 8MB  query bf16 (t,b,e)
  u16* wqb  = (u16*)(ws + 8 * MB);      // 2MB
  u16* wkb  = (u16*)(ws + 10 * MB);
  u16* wvb  = (u16*)(ws + 12 * MB);
  u16* wob  = (u16*)(ws + 14 * MB);
  u16* qav  = (u16*)(ws + 16 * MB);     // 8MB  [b,h,t,d] (log2-scaled Q)
  u16* kav  = (u16*)(ws + 24 * MB);     // 8MB  [b,h,t,d]
  u16* vtv  = (u16*)(ws + 32 * MB);     // 8MB  [b,h,d,t]
  u16* aout = (u16*)(ws + 40 * MB);     // 8MB  attn out (t,b,e) bf16
  float* lut  = (float*)(ws + 48 * MB);              // 256KB [h][4096], log2 dom
  float* gate = (float*)(ws + 48 * MB + 256 * 1024); // 256KB [b,h,t]

  convk<<<dim3(4096), 256, 0, stream>>>(query, qbf, 1048576);
  convk<<<dim3(1024), 256, 0, stream>>>(q_w, wqb, 262144);
  convk<<<dim3(1024), 256, 0, stream>>>(k_w, wkb, 262144);
  convk<<<dim3(1024), 256, 0, stream>>>(v_w, wvb, 262144);
  convk<<<dim3(1024), 256, 0, stream>>>(out_w, wob, 262144);
  lutk<<<dim3(16), 256, 0, stream>>>(rel_emb, lut);
  gatek<<<dim3(256), 256, 0, stream>>>(query, grep_w, grep_b, grep_a, gate);

  gemmk<<<dim3(8, 32, 3), 256, 0, stream>>>(qbf, wqb, wkb, wvb, q_b, k_b, v_b,
                                            qav, kav, vtv, nullptr, 0);
  flashk<<<dim3(512), 256, 0, stream>>>(qav, kav, vtv, lut, gate, aout);
  gemmk<<<dim3(8, 32, 1), 256, 0, stream>>>(aout, wob, nullptr, nullptr, out_b, nullptr, nullptr,
                                            nullptr, nullptr, nullptr, (float*)d_out, 3);
}

// Round 5
// 166.578 us; speedup vs baseline: 1.3614x; 1.1024x over previous
//
#include <hip/hip_runtime.h>
#include <math.h>

typedef unsigned short u16;
typedef unsigned int u32;
typedef __bf16 bf16x8 __attribute__((ext_vector_type(8)));
typedef float f32x4 __attribute__((ext_vector_type(4)));
typedef float f32x16 __attribute__((ext_vector_type(16)));

// ---------- helpers ----------
__device__ __forceinline__ u16 f2bf(float f) {
  union { float f; u32 u; } v; v.f = f;
  u32 r = v.u + 0x7fffu + ((v.u >> 16) & 1u);
  return (u16)(r >> 16);
}

__device__ __forceinline__ u32 pkbf(float a, float b) {
  u32 r;
  asm("v_cvt_pk_bf16_f32 %0, %1, %2" : "=v"(r) : "v"(a), "v"(b));
  return r;
}

// v_exp_f32 computes 2^x (log2 domain)
__device__ __forceinline__ float ex2(float x) {
  float r;
  asm("v_exp_f32 %0, %1" : "=v"(r) : "v"(x));
  return r;
}

// async global->LDS, 16B per lane. LDS dest wave-uniform base; HW adds lane*16.
__device__ __forceinline__ void gld16(const void* g, void* s) {
  __builtin_amdgcn_global_load_lds(
      reinterpret_cast<__attribute__((address_space(1))) u32*>((size_t)g),
      reinterpret_cast<__attribute__((address_space(3))) u32*>((u32)(size_t)s),
      16, 0, 0);
}

// ---------- prep: fp32 -> bf16 (vectorized) ----------
__global__ __launch_bounds__(256) void convk(const float* __restrict__ src,
                                             u16* __restrict__ dst, int n4) {
  int i = blockIdx.x * 256 + threadIdx.x;
  if (i >= n4) return;
  float4 v = ((const float4*)src)[i];
  uint2 o;
  o.x = (u32)f2bf(v.x) | ((u32)f2bf(v.y) << 16);
  o.y = (u32)f2bf(v.z) | ((u32)f2bf(v.w) << 16);
  ((uint2*)dst)[i] = o;
}

// ---------- prep: rel-pos LUT in LOG2 domain: lut[h][dix], dix = (s-t)+2048 ----------
__global__ __launch_bounds__(256) void lutk(const float* __restrict__ rel_emb,
                                            float* __restrict__ lut) {
  int dix = blockIdx.x * 256 + threadIdx.x;
  if (dix >= 4096) return;
  int rp = dix - 2048;                 // rp = s - t
  int bucket = (rp > 0) ? 16 : 0;
  int rpa = rp < 0 ? -rp : rp;
  if (rpa < 8) {
    bucket += rpa;
  } else {
    int large = 8 + (int)(logf((float)rpa * 0.125f) * (8.0f / 2.772588722239781f));
    bucket += (large < 15) ? large : 15;
  }
  const float LOG2E = 1.4426950408889634f;
#pragma unroll
  for (int h = 0; h < 16; ++h) lut[h * 4096 + dix] = rel_emb[bucket * 16 + h] * LOG2E;
}

// ---------- prep: gate_a_1[b,h,t] (exact fp32) ----------
__global__ __launch_bounds__(256) void gatek(const float* __restrict__ query,
                                             const float* __restrict__ grep_w,
                                             const float* __restrict__ grep_b,
                                             const float* __restrict__ grep_a,
                                             float* __restrict__ gate) {
  __shared__ __align__(16) float gw[8][64];
  __shared__ float gb[8];
  __shared__ float ga[16];
  int tid = threadIdx.x;
  if (tid < 128) ((float4*)&gw[0][0])[tid] = ((const float4*)grep_w)[tid];
  if (tid < 8) gb[tid] = grep_b[tid];
  if (tid < 16) ga[tid] = grep_a[tid];
  __syncthreads();
  int i = blockIdx.x * 256 + tid;          // i = ((b*16+h)*2048 + t)
  int t = i & 2047, h = (i >> 11) & 15, b = i >> 15;
  const float* x = query + ((size_t)t * 2 + b) * 1024 + h * 64;
  float acc[8] = {0, 0, 0, 0, 0, 0, 0, 0};
  for (int e4 = 0; e4 < 16; ++e4) {
    float4 xv = ((const float4*)x)[e4];
#pragma unroll
    for (int j = 0; j < 8; ++j)
      acc[j] += xv.x * gw[j][e4 * 4] + xv.y * gw[j][e4 * 4 + 1] +
                xv.z * gw[j][e4 * 4 + 2] + xv.w * gw[j][e4 * 4 + 3];
  }
  float sA = acc[0] + acc[1] + acc[2] + acc[3] + gb[0] + gb[1] + gb[2] + gb[3];
  float sB = acc[4] + acc[5] + acc[6] + acc[7] + gb[4] + gb[5] + gb[6] + gb[7];
  float gA = 1.0f / (1.0f + expf(-sA));
  float gB = 1.0f / (1.0f + expf(-sB));
  gate[i] = gA * (gB * ga[h] - 1.0f) + 2.0f;
}

// ---------- GEMM: C[m][n] = A[m][:] . W[n][:] (+bias), bf16 MFMA, 128x128 tile, BK=64 ----------
// mode 0: q -> qa[b,h,t,d] * QSC ; mode 1: k -> kstage fragment-major tiles
// mode 2: v -> vstage fragment-major tiles ; mode 3: out-proj -> fout fp32
// kstage[bh][tile(64)][slot(8)][srow(32)][8] : slot*8+j = d, srow = s&31
// vstage[bh][tile(64)][slot(4)][d(64)][8]    : slot*8+j = s&31 sub-col, rows = d
__global__ __launch_bounds__(256) void gemmk(
    const u16* __restrict__ A,
    const u16* __restrict__ W0, const u16* __restrict__ W1, const u16* __restrict__ W2,
    const float* __restrict__ b0, const float* __restrict__ b1, const float* __restrict__ b2,
    u16* __restrict__ qa, u16* __restrict__ kst, u16* __restrict__ vst,
    float* __restrict__ fout, int moBase) {
  const int mode = moBase + (int)blockIdx.z;
  const u16* W = (mode == 1) ? W1 : (mode == 2) ? W2 : W0;
  const float* bias = (mode == 1) ? b1 : (mode == 2) ? b2 : b0;

  __shared__ __align__(16) u16 As[128 * 64];   // [row][64] bf16, 8 16B-slots/row, slot^=(row&7)
  __shared__ __align__(16) u16 Bs[128 * 64];

  const int tid = threadIdx.x;
  const int l = tid & 63;
  const int w = tid >> 6;
  const int wr = w >> 1, wc = w & 1;
  const int m0 = blockIdx.y * 128, n0 = blockIdx.x * 128;
  const int li = l >> 3, ls = l & 7;

  f32x4 acc[4][4] = {};

  for (int k0 = 0; k0 < 1024; k0 += 64) {
#pragma unroll
    for (int j = 0; j < 4; ++j) {
      const int rr = (w * 4 + j) * 8 + li;
      const int cs = ls ^ (rr & 7);
      gld16(A + ((size_t)(m0 + rr) << 10) + k0 + cs * 8, &As[(w * 4 + j) * 512]);
      gld16(W + ((size_t)(n0 + rr) << 10) + k0 + cs * 8, &Bs[(w * 4 + j) * 512]);
    }
    __syncthreads();
#pragma unroll
    for (int ks = 0; ks < 2; ++ks) {
      bf16x8 af[4], bfr[4];
#pragma unroll
      for (int mf = 0; mf < 4; ++mf) {
        const int row = wr * 64 + mf * 16 + (l & 15);
        const int slot = (ks * 4 + (l >> 4)) ^ (row & 7);
        af[mf] = *(const bf16x8*)&As[row * 64 + slot * 8];
      }
#pragma unroll
      for (int nf = 0; nf < 4; ++nf) {
        const int row = wc * 64 + nf * 16 + (l & 15);
        const int slot = (ks * 4 + (l >> 4)) ^ (row & 7);
        bfr[nf] = *(const bf16x8*)&Bs[row * 64 + slot * 8];
      }
#pragma unroll
      for (int mf = 0; mf < 4; ++mf)
#pragma unroll
        for (int nf = 0; nf < 4; ++nf)
          acc[mf][nf] = __builtin_amdgcn_mfma_f32_16x16x32_bf16(af[mf], bfr[nf], acc[mf][nf], 0, 0, 0);
    }
    __syncthreads();
  }

  const float QSC = 0.125f * 1.4426950408889634f;  // HD^-0.5 * log2(e): Q in log2 domain
#pragma unroll
  for (int mf = 0; mf < 4; ++mf)
#pragma unroll
    for (int nf = 0; nf < 4; ++nf)
#pragma unroll
      for (int r = 0; r < 4; ++r) {
        const int row = m0 + wr * 64 + mf * 16 + (l >> 4) * 4 + r;  // m = t*2+b
        const int col = n0 + wc * 64 + nf * 16 + (l & 15);          // n = h*64+d
        float v = acc[mf][nf][r] + bias[col];
        const int t = row >> 1, bb = row & 1, hh = col >> 6, d = col & 63;
        const size_t bh = (size_t)bb * 16 + hh;
        if (mode == 0) {
          v *= QSC;
          qa[((bh * 2048 + t) << 6) + d] = f2bf(v);
        } else if (mode == 1) {
          // kstage: ((bh*64 + t>>5)*2048) + (d>>3)*256 + (t&31)*8 + (d&7)
          kst[((bh * 64 + (t >> 5)) << 11) + ((d >> 3) << 8) + ((t & 31) << 3) + (d & 7)] = f2bf(v);
        } else if (mode == 2) {
          // vstage: ((bh*64 + t>>5)*2048) + ((t>>3)&3)*512 + d*8 + (t&7)
          vst[((bh * 64 + (t >> 5)) << 11) + (((t >> 3) & 3) << 9) + (d << 3) + (t & 7)] = f2bf(v);
        } else {
          fout[((size_t)row << 10) + col] = v;
        }
      }
}

// ---------- flash attention v4: fragment-major LDS tiles + in-block KV-split x2 ----------
// Block = 64 q-rows, 4 waves: wave (half = w>>1, sub = w&1) owns q-rows qt*64+sub*32,
// s in [half*1024, half*1024+1024). Staging: sub0 stages K (4x gld16), sub1 stages V,
// from pre-permuted kstage/vstage -> linear coalesced loads AND conflict-free ds_reads.
// 2-way m/l/O combine in LDS at the end. 4 blocks/CU (16 waves).
__global__ __launch_bounds__(256, 4) void flashk(const u16* __restrict__ qa,
                                                 const u16* __restrict__ kst,
                                                 const u16* __restrict__ vst,
                                                 const float* __restrict__ lutg,
                                                 const float* __restrict__ gatew,
                                                 u16* __restrict__ aout) {
  const int B = blockIdx.x;
  const int xcd = B & 7, j = B >> 3;
  const int bh = xcd * 4 + (j >> 5);       // 4 heads per XCD (K/V L2-resident)
  const int qt = j & 31;
  const int hh = bh & 15, b = bh >> 4;
  const int tid = threadIdx.x, l = tid & 63, w = tid >> 6;
  const int half = w >> 1, sub = w & 1;
  const int hi = l >> 5, q = l & 31;
  const int q0b = qt * 64;
  const int q0w = q0b + sub * 32;          // this wave's 32-row q-window
  const int qg = q0w + q;

  __shared__ union {
    struct { u16 K[2][2][2048]; u16 V[2][2][2048]; } m;              // 32KB main
    struct { float pm[4][32]; float pl[4][32]; float pO[4][32][68]; } c;  // combine
  } S;
  __shared__ __align__(16) float slice[288];   // lut band, dix0=1920 -> s-t in [-128,160)

  for (int i = tid; i < 288; i += 256) slice[i] = lutg[hh * 4096 + 1920 + i];

  const size_t tb0 = (size_t)bh * 64;      // tile index base
  const u16* Q = qa + ((size_t)bh << 17);

  // Q B-frags: lane n=q, k-dim = mk*16 + hi*8 + j
  bf16x8 qf[4];
#pragma unroll
  for (int mk = 0; mk < 4; ++mk)
    qf[mk] = *(const bf16x8*)&Q[((size_t)qg << 6) + mk * 16 + hi * 8];

  const float g = gatew[((size_t)bh << 11) + qg];
  const float gcm = g * lutg[hh * 4096];          // far-minus bias (log2 dom)
  const float gcp = g * lutg[hh * 4096 + 4095];   // far-plus bias

  float m_run = -3e38f, l_run = 0.0f;
  f32x16 oacc[2] = {};

  // prologue: stage tile (half*32) into buf 0. Lane offset l*16B linear.
  {
    const u16* kt0 = kst + ((tb0 + half * 32) << 11) + l * 8;
    const u16* vt0 = vst + ((tb0 + half * 32) << 11) + l * 8;
    if (sub == 0) {
#pragma unroll
      for (int i = 0; i < 4; ++i) gld16(kt0 + i * 512, &S.m.K[half][0][i * 512]);
    } else {
#pragma unroll
      for (int i = 0; i < 4; ++i) gld16(vt0 + i * 512, &S.m.V[half][0][i * 512]);
    }
  }
  __syncthreads();

  for (int ts = 0; ts < 32; ++ts) {
    const int bf_ = ts & 1;
    // prefetch next tile into other buffer
    if (ts < 31) {
      const u16* ktn = kst + ((tb0 + half * 32 + ts + 1) << 11) + l * 8;
      const u16* vtn = vst + ((tb0 + half * 32 + ts + 1) << 11) + l * 8;
      if (sub == 0) {
#pragma unroll
        for (int i = 0; i < 4; ++i) gld16(ktn + i * 512, &S.m.K[half][bf_ ^ 1][i * 512]);
      } else {
#pragma unroll
        for (int i = 0; i < 4; ++i) gld16(vtn + i * 512, &S.m.V[half][bf_ ^ 1][i * 512]);
      }
    }
    const u16* Kb = &S.m.K[half][bf_][0];
    const u16* Vb = &S.m.V[half][bf_][0];
    const int s0 = half * 1024 + ts * 32;

    // S^T tile: C[k_local][q], k_local = (reg&3)+8*(reg>>2)+4*hi
    f32x16 s = {};
#pragma unroll
    for (int mk = 0; mk < 4; ++mk) {
      bf16x8 kf = *(const bf16x8*)&Kb[(mk * 2 + hi) * 256 + q * 8];
      s = __builtin_amdgcn_mfma_f32_32x32x16_bf16(kf, qf[mk], s, 0, 0, 0);
    }

    const int kt = (s0 - q0w) >> 5;
    const bool far = (kt <= -4) | (kt >= 4);
    float gc = 0.0f;
    float mx;
    if (far) {
      gc = (kt < 0) ? gcm : gcp;
      float t0_ = fmaxf(fmaxf(s[0], s[1]), s[2]);
      float t1_ = fmaxf(fmaxf(s[3], s[4]), s[5]);
      float t2_ = fmaxf(fmaxf(s[6], s[7]), s[8]);
      float t3_ = fmaxf(fmaxf(s[9], s[10]), s[11]);
      float t4_ = fmaxf(fmaxf(s[12], s[13]), s[14]);
      mx = fmaxf(fmaxf(fmaxf(t0_, t1_), t2_), fmaxf(fmaxf(t3_, t4_), s[15]));
      mx = fmaxf(mx, __shfl_xor(mx, 32, 64)) + gc;
    } else {
      const int sb = s0 - q0w + 128 + 4 * hi - q;
#pragma unroll
      for (int reg = 0; reg < 16; ++reg) {
        const int kloc = (reg & 3) + 8 * (reg >> 2);
        s[reg] = fmaf(g, slice[sb + kloc], s[reg]);
      }
      float t0_ = fmaxf(fmaxf(s[0], s[1]), s[2]);
      float t1_ = fmaxf(fmaxf(s[3], s[4]), s[5]);
      float t2_ = fmaxf(fmaxf(s[6], s[7]), s[8]);
      float t3_ = fmaxf(fmaxf(s[9], s[10]), s[11]);
      float t4_ = fmaxf(fmaxf(s[12], s[13]), s[14]);
      mx = fmaxf(fmaxf(fmaxf(t0_, t1_), t2_), fmaxf(fmaxf(t3_, t4_), s[15]));
      mx = fmaxf(mx, __shfl_xor(mx, 32, 64));
    }
    // defer-max (T13), log2 domain threshold ~ 8*log2e
    if (!__all(mx - m_run <= 11.5f)) {
      const float mnew = fmaxf(m_run, mx);
      const float sc = ex2(m_run - mnew);
      l_run *= sc;
#pragma unroll
      for (int r = 0; r < 16; ++r) { oacc[0][r] *= sc; oacc[1][r] *= sc; }
      m_run = mnew;
    }
    // P = 2^(S - mref), tree row-sum
    const float mref = m_run - gc;
#pragma unroll
    for (int reg = 0; reg < 16; ++reg) s[reg] = ex2(s[reg] - mref);
    {
      float r0 = (s[0] + s[1]) + (s[2] + s[3]);
      float r1 = (s[4] + s[5]) + (s[6] + s[7]);
      float r2 = (s[8] + s[9]) + (s[10] + s[11]);
      float r3 = (s[12] + s[13]) + (s[14] + s[15]);
      float rsum = (r0 + r1) + (r2 + r3);
      rsum += __shfl_xor(rsum, 32, 64);
      l_run += rsum;
    }
    // pack P -> PV B-frags (T12)
    bf16x8 pa[2];
#pragma unroll
    for (int kh = 0; kh < 2; ++kh) {
      const int rb = kh * 8;
      const u32 X0 = pkbf(s[rb + 0], s[rb + 1]);
      const u32 X1 = pkbf(s[rb + 2], s[rb + 3]);
      const u32 Y0 = pkbf(s[rb + 4], s[rb + 5]);
      const u32 Y1 = pkbf(s[rb + 6], s[rb + 7]);
      const u32 E0 = hi ? X0 : Y0;
      const u32 E1 = hi ? X1 : Y1;
      const u32 Ep0 = (u32)__shfl_xor((int)E0, 32, 64);
      const u32 Ep1 = (u32)__shfl_xor((int)E1, 32, 64);
      union { u32 wds[4]; bf16x8 v; } pu;
      pu.wds[0] = hi ? Ep0 : X0;
      pu.wds[1] = hi ? Ep1 : X1;
      pu.wds[2] = hi ? Y0 : Ep0;
      pu.wds[3] = hi ? Y1 : Ep1;
      pa[kh] = pu.v;
    }
    // O^T += V^T . P  (V frags fragment-major: conflict-free)
#pragma unroll
    for (int dt = 0; dt < 2; ++dt)
#pragma unroll
      for (int kh = 0; kh < 2; ++kh) {
        bf16x8 vf = *(const bf16x8*)&Vb[(kh * 2 + hi) * 512 + dt * 256 + q * 8];
        oacc[dt] = __builtin_amdgcn_mfma_f32_32x32x16_bf16(vf, pa[kh], oacc[dt], 0, 0, 0);
      }
    __syncthreads();
  }

  // ---- 2-way combine: waves (sub, sub+2) share q-rows ----
  __syncthreads();   // all reads of K/V done; repurpose LDS
  if (hi == 0) { S.c.pm[w][q] = m_run; S.c.pl[w][q] = l_run; }
#pragma unroll
  for (int dt = 0; dt < 2; ++dt)
#pragma unroll
    for (int g4 = 0; g4 < 4; ++g4) {
      float4 v4;
      v4.x = oacc[dt][g4 * 4 + 0];
      v4.y = oacc[dt][g4 * 4 + 1];
      v4.z = oacc[dt][g4 * 4 + 2];
      v4.w = oacc[dt][g4 * 4 + 3];
      *(float4*)&S.c.pO[w][q][dt * 32 + g4 * 8 + hi * 4] = v4;
    }
  __syncthreads();

  const int rr = tid >> 2;                 // 0..63 block-local q-row
  const int dc = (tid & 3) << 4;           // 0,16,32,48
  const int rl = rr & 31, sr = rr >> 5;
  const float mA = S.c.pm[sr][rl], mB = S.c.pm[2 + sr][rl];
  const float M = fmaxf(mA, mB);
  const float eA = ex2(mA - M), eB = ex2(mB - M);
  const float inv = 1.0f / (S.c.pl[sr][rl] * eA + S.c.pl[2 + sr][rl] * eB);
  union { u16 hb[16]; uint4 u4[2]; } st;
#pragma unroll
  for (int c4 = 0; c4 < 4; ++c4) {
    const float4 a = *(const float4*)&S.c.pO[sr][rl][dc + c4 * 4];
    const float4 bb = *(const float4*)&S.c.pO[2 + sr][rl][dc + c4 * 4];
    st.hb[c4 * 4 + 0] = f2bf((a.x * eA + bb.x * eB) * inv);
    st.hb[c4 * 4 + 1] = f2bf((a.y * eA + bb.y * eB) * inv);
    st.hb[c4 * 4 + 2] = f2bf((a.z * eA + bb.z * eB) * inv);
    st.hb[c4 * 4 + 3] = f2bf((a.w * eA + bb.w * eB) * inv);
  }
  u16* dst = &aout[(((size_t)(q0b + rr) * 2 + b) << 10) + hh * 64 + dc];
  *(uint4*)dst = st.u4[0];
  *(uint4*)(dst + 8) = st.u4[1];
}

// ---------- launch ----------
extern "C" void kernel_launch(void* const* d_in, const int* in_sizes, int n_in,
                              void* d_out, int out_size, void* d_ws, size_t ws_size,
                              hipStream_t stream) {
  (void)in_sizes; (void)n_in; (void)out_size; (void)ws_size;
  const float* query  = (const float*)d_in[0];
  const float* q_w    = (const float*)d_in[1];
  const float* q_b    = (const float*)d_in[2];
  const float* k_w    = (const float*)d_in[3];
  const float* k_b    = (const float*)d_in[4];
  const float* v_w    = (const float*)d_in[5];
  const float* v_b    = (const float*)d_in[6];
  const float* out_w  = (const float*)d_in[7];
  const float* out_b  = (const float*)d_in[8];
  const float* rel_emb= (const float*)d_in[9];
  const float* grep_w = (const float*)d_in[10];
  const float* grep_b = (const float*)d_in[11];
  const float* grep_a = (const float*)d_in[12];

  char* ws = (char*)d_ws;
  const size_t MB = 1ull << 20;
  u16* qbf  = (u16*)(ws + 0 * MB);      // 8MB  query bf16 (t,b,e)
  u16* wqb  = (u16*)(ws + 8 * MB);      // 2MB
  u16* wkb  = (u16*)(ws + 10 * MB);
  u16* wvb  = (u16*)(ws + 12 * MB);
  u16* wob  = (u16*)(ws + 14 * MB);
  u16* qav  = (u16*)(ws + 16 * MB);     // 8MB  [b,h,t,d] (log2-scaled Q)
  u16* kstg = (u16*)(ws + 24 * MB);     // 8MB  fragment-major K tiles
  u16* vstg = (u16*)(ws + 32 * MB);     // 8MB  fragment-major V tiles
  u16* aout = (u16*)(ws + 40 * MB);     // 8MB  attn out (t,b,e) bf16
  float* lut  = (float*)(ws + 48 * MB);              // 256KB [h][4096], log2 dom
  float* gate = (float*)(ws + 48 * MB + 256 * 1024); // 256KB [b,h,t]

  convk<<<dim3(4096), 256, 0, stream>>>(query, qbf, 1048576);
  convk<<<dim3(1024), 256, 0, stream>>>(q_w, wqb, 262144);
  convk<<<dim3(1024), 256, 0, stream>>>(k_w, wkb, 262144);
  convk<<<dim3(1024), 256, 0, stream>>>(v_w, wvb, 262144);
  convk<<<dim3(1024), 256, 0, stream>>>(out_w, wob, 262144);
  lutk<<<dim3(16), 256, 0, stream>>>(rel_emb, lut);
  gatek<<<dim3(256), 256, 0, stream>>>(query, grep_w, grep_b, grep_a, gate);

  gemmk<<<dim3(8, 32, 3), 256, 0, stream>>>(qbf, wqb, wkb, wvb, q_b, k_b, v_b,
                                            qav, kstg, vstg, nullptr, 0);
  flashk<<<dim3(1024), 256, 0, stream>>>(qav, kstg, vstg, lut, gate, aout);
  gemmk<<<dim3(8, 32, 1), 256, 0, stream>>>(aout, wob, nullptr, nullptr, out_b, nullptr, nullptr,
                                            nullptr, nullptr, nullptr, (float*)d_out, 3);
}